// Round 1
// baseline (17101.096 us; speedup 1.0000x reference)
//
#include <hip/hip_runtime.h>
#include <math.h>

// Problem constants (from reference)
#define HH   512      // hidden
#define BB   32       // batch
#define TENC 256      // encoder steps
#define TDEC 32       // decoder steps
#define VV   50000    // vocab
#define SOSTOK 2
#define G3H  1536     // 3*H
#define NCG  49       // ceil(50000/1024) logits col-groups

__device__ __forceinline__ float sigmoidf_(float x) { return 1.0f / (1.0f + expf(-x)); }

// ---------------------------------------------------------------------------
// gx kernel: out[m][j] = dot(A_row(m), W[j,:]) + bias[j]
// A_row(m) = emb[idx(m)] (enc) or relu(emb[idx(m)]) with SOS shift (dec).
// m = t*32 + b. W is [3H, H] row-major (k-contiguous rows) -> "NT" gemm.
// Block: 16 rows x 1024 cols (256 thr, 4 j/thread, acc[16][4]).
// grid.x = M/16 (row groups), grid.y = 2 (col groups of 1024; N=1536).
// ---------------------------------------------------------------------------
__global__ __launch_bounds__(256) void gx_kernel(
    const int* __restrict__ idxs, const float* __restrict__ emb,
    const float* __restrict__ W, const float* __restrict__ bias,
    float* __restrict__ out, int dec_mode)
{
    __shared__ __align__(16) float As[16][HH];
    const int tid = threadIdx.x;
    const int m0 = blockIdx.x * 16;

    // Stage 16 gathered A rows into LDS (coalesced along k)
    for (int l = tid; l < 16 * HH; l += 256) {
        int r = l >> 9, k = l & (HH - 1);
        int m = m0 + r;
        int t = m >> 5, b = m & 31;
        int idx;
        if (dec_mode) idx = (t == 0) ? SOSTOK : idxs[b * TDEC + (t - 1)];
        else          idx = idxs[b * TENC + t];
        float v = emb[(size_t)idx * HH + k];
        if (dec_mode) v = fmaxf(v, 0.0f);
        As[r][k] = v;
    }
    __syncthreads();

    const int j0 = blockIdx.y * 1024 + tid * 4;
    if (j0 >= G3H) return;   // second col-group only covers 512 cols

    float acc[16][4];
#pragma unroll
    for (int r = 0; r < 16; r++)
#pragma unroll
        for (int jj = 0; jj < 4; jj++) acc[r][jj] = 0.0f;

    const float* w0p = W + (size_t)(j0 + 0) * HH;
    const float* w1p = W + (size_t)(j0 + 1) * HH;
    const float* w2p = W + (size_t)(j0 + 2) * HH;
    const float* w3p = W + (size_t)(j0 + 3) * HH;

    for (int kc = 0; kc < HH; kc += 4) {
        float4 w0 = *(const float4*)(w0p + kc);
        float4 w1 = *(const float4*)(w1p + kc);
        float4 w2 = *(const float4*)(w2p + kc);
        float4 w3 = *(const float4*)(w3p + kc);
#pragma unroll
        for (int r = 0; r < 16; r++) {
            float4 a = *(const float4*)(&As[r][kc]);
            acc[r][0] += a.x * w0.x + a.y * w0.y + a.z * w0.z + a.w * w0.w;
            acc[r][1] += a.x * w1.x + a.y * w1.y + a.z * w1.z + a.w * w1.w;
            acc[r][2] += a.x * w2.x + a.y * w2.y + a.z * w2.z + a.w * w2.w;
            acc[r][3] += a.x * w3.x + a.y * w3.y + a.z * w3.z + a.w * w3.w;
        }
    }

    float4 bv = *(const float4*)(bias + j0);
#pragma unroll
    for (int r = 0; r < 16; r++) {
        float4 o;
        o.x = acc[r][0] + bv.x;
        o.y = acc[r][1] + bv.y;
        o.z = acc[r][2] + bv.z;
        o.w = acc[r][3] + bv.w;
        *(float4*)(out + (size_t)(m0 + r) * G3H + j0) = o;
    }
}

// ---------------------------------------------------------------------------
// One GRU step: gh = h_in @ Whh^T (+bhh), then elementwise gate math.
// grid = 32 blocks x 256 thr = 8192 threads; thread = (b-pair, i).
// Lanes are i-consecutive -> Whh row lines reused from L1 across k;
// h_in reads are wave-broadcast. ~48 MB/step Whh traffic from L2.
// h_in / h_out are distinct buffers (ping-pong) -> no intra-step race.
// ---------------------------------------------------------------------------
__global__ __launch_bounds__(256) void gru_step_kernel(
    const float* __restrict__ gx_t,   // [B][3H] for this step (includes bih)
    const float* __restrict__ Whh,    // [3H][H]
    const float* __restrict__ bhh,    // [3H]
    const float* __restrict__ h_in,   // [B][H]
    float* __restrict__ h_out)        // [B][H]
{
    const int flat = blockIdx.x * 256 + threadIdx.x;   // 0..8191
    const int i  = flat & (HH - 1);
    const int b0 = (flat >> 9) * 2;                    // handles b0, b0+1

    const float* wr = Whh + (size_t)i * HH;
    const float* wz = Whh + (size_t)(HH + i) * HH;
    const float* wn = Whh + (size_t)(2 * HH + i) * HH;
    const float* h0p = h_in + (size_t)b0 * HH;
    const float* h1p = h0p + HH;

    float ar0 = 0.f, az0 = 0.f, an0 = 0.f;
    float ar1 = 0.f, az1 = 0.f, an1 = 0.f;

    for (int k = 0; k < HH; k += 4) {
        float4 hr0 = *(const float4*)(h0p + k);
        float4 hr1 = *(const float4*)(h1p + k);
        float4 w_r = *(const float4*)(wr + k);
        float4 w_z = *(const float4*)(wz + k);
        float4 w_n = *(const float4*)(wn + k);
        ar0 += hr0.x * w_r.x + hr0.y * w_r.y + hr0.z * w_r.z + hr0.w * w_r.w;
        az0 += hr0.x * w_z.x + hr0.y * w_z.y + hr0.z * w_z.z + hr0.w * w_z.w;
        an0 += hr0.x * w_n.x + hr0.y * w_n.y + hr0.z * w_n.z + hr0.w * w_n.w;
        ar1 += hr1.x * w_r.x + hr1.y * w_r.y + hr1.z * w_r.z + hr1.w * w_r.w;
        az1 += hr1.x * w_z.x + hr1.y * w_z.y + hr1.z * w_z.z + hr1.w * w_z.w;
        an1 += hr1.x * w_n.x + hr1.y * w_n.y + hr1.z * w_n.z + hr1.w * w_n.w;
    }

    const float bhr = bhh[i], bhz = bhh[HH + i], bhn = bhh[2 * HH + i];
#pragma unroll
    for (int bb = 0; bb < 2; bb++) {
        const int b = b0 + bb;
        const float dr = bb ? ar1 : ar0;
        const float dz = bb ? az1 : az0;
        const float dn = bb ? an1 : an0;
        const float* gx = gx_t + (size_t)b * G3H;
        float r = sigmoidf_(gx[i]          + dr + bhr);
        float z = sigmoidf_(gx[HH + i]     + dz + bhz);
        float n = tanhf    (gx[2 * HH + i] + r * (dn + bhn));
        float hp = h_in[(size_t)b * HH + i];
        h_out[(size_t)b * HH + i] = (1.0f - z) * n + z * hp;
    }
}

// ---------------------------------------------------------------------------
// Fused logits GEMM + per-row partial logsumexp + target-logit gather.
// C[m][j] = dot(Hall[m], Wg[:,j]) + bg[j];   Wg is [K=512][V] (j-contiguous!)
// Block: 16 rows x 1024 cols. grid = (64 rowgroups, 49 colgroups); rowgroup
// is the FAST grid index so all rowgroups of one Wg slice run concurrently
// (slice reused from L2/L3; HBM reads Wg ~once).
// Writes per-colgroup partial (max, sumexp) + target logits.
// ---------------------------------------------------------------------------
__global__ __launch_bounds__(256) void logits_kernel(
    const float* __restrict__ Hall,   // [1024][512]
    const float* __restrict__ Wg,     // [512][50000]
    const float* __restrict__ bg,     // [50000]
    const int* __restrict__ qw,       // [32][32] targets
    float* __restrict__ pmax,         // [49][1024]
    float* __restrict__ psum,         // [49][1024]
    float* __restrict__ tgt_logit)    // [1024]
{
    __shared__ __align__(16) float As[16][HH];
    __shared__ float wred[16][4];
    const int tid = threadIdx.x;
    const int m0 = blockIdx.x * 16;
    const int lane = tid & 63, wid = tid >> 6;

    for (int l = tid; l < 16 * HH; l += 256) {
        int r = l >> 9, k = l & (HH - 1);
        As[r][k] = Hall[(size_t)(m0 + r) * HH + k];
    }
    __syncthreads();

    const int j0 = blockIdx.y * 1024 + tid * 4;
    const bool valid = (j0 < VV);   // V=50000 divisible by 4 -> whole float4 valid

    float acc[16][4];
#pragma unroll
    for (int r = 0; r < 16; r++)
#pragma unroll
        for (int jj = 0; jj < 4; jj++) acc[r][jj] = 0.0f;

    if (valid) {
        for (int kc = 0; kc < HH; kc += 4) {
            float4 w0 = *(const float4*)(Wg + (size_t)(kc + 0) * VV + j0);
            float4 w1 = *(const float4*)(Wg + (size_t)(kc + 1) * VV + j0);
            float4 w2 = *(const float4*)(Wg + (size_t)(kc + 2) * VV + j0);
            float4 w3 = *(const float4*)(Wg + (size_t)(kc + 3) * VV + j0);
#pragma unroll
            for (int r = 0; r < 16; r++) {
                float4 a = *(const float4*)(&As[r][kc]);
                acc[r][0] += a.x * w0.x + a.y * w1.x + a.z * w2.x + a.w * w3.x;
                acc[r][1] += a.x * w0.y + a.y * w1.y + a.z * w2.y + a.w * w3.y;
                acc[r][2] += a.x * w0.z + a.y * w1.z + a.z * w2.z + a.w * w3.z;
                acc[r][3] += a.x * w0.w + a.y * w1.w + a.z * w2.w + a.w * w3.w;
            }
        }
        float4 bv = *(const float4*)(bg + j0);
#pragma unroll
        for (int r = 0; r < 16; r++) {
            acc[r][0] += bv.x; acc[r][1] += bv.y; acc[r][2] += bv.z; acc[r][3] += bv.w;
        }
        // target-logit gather: unique (row, col) writer across the whole grid
#pragma unroll
        for (int r = 0; r < 16; r++) {
            int m = m0 + r, t = m >> 5, b = m & 31;
            int tj = qw[b * TDEC + t];
            if (tj >= j0 && tj < j0 + 4) tgt_logit[m] = acc[r][tj - j0];
        }
    }

    // per-row block max
    float rowmax[16];
#pragma unroll
    for (int r = 0; r < 16; r++) {
        float v = valid ? fmaxf(fmaxf(acc[r][0], acc[r][1]), fmaxf(acc[r][2], acc[r][3]))
                        : -INFINITY;
        for (int off = 32; off > 0; off >>= 1) v = fmaxf(v, __shfl_xor(v, off));
        if (lane == 0) wred[r][wid] = v;
    }
    __syncthreads();
#pragma unroll
    for (int r = 0; r < 16; r++)
        rowmax[r] = fmaxf(fmaxf(wred[r][0], wred[r][1]), fmaxf(wred[r][2], wred[r][3]));
    __syncthreads();

    // per-row block sum of exp
#pragma unroll
    for (int r = 0; r < 16; r++) {
        float s = 0.0f;
        if (valid) {
            s = expf(acc[r][0] - rowmax[r]) + expf(acc[r][1] - rowmax[r])
              + expf(acc[r][2] - rowmax[r]) + expf(acc[r][3] - rowmax[r]);
        }
        for (int off = 32; off > 0; off >>= 1) s += __shfl_xor(s, off);
        if (lane == 0) wred[r][wid] = s;
    }
    __syncthreads();

    if (tid < 16) {
        int r = tid;
        float S = wred[r][0] + wred[r][1] + wred[r][2] + wred[r][3];
        pmax[blockIdx.y * 1024 + m0 + r] = rowmax[r];
        psum[blockIdx.y * 1024 + m0 + r] = S;
    }
}

// ---------------------------------------------------------------------------
// Combine col-group partials -> per-row lse -> loss = sum(lse - tgt)/Tdec
// ---------------------------------------------------------------------------
__global__ __launch_bounds__(256) void loss_kernel(
    const float* __restrict__ pmax, const float* __restrict__ psum,
    const float* __restrict__ tgt_logit, float* __restrict__ out)
{
    const int tid = threadIdx.x;
    float local = 0.0f;
    for (int m = tid; m < 1024; m += 256) {
        float M = -INFINITY;
        for (int cg = 0; cg < NCG; cg++) M = fmaxf(M, pmax[cg * 1024 + m]);
        float S = 0.0f;
        for (int cg = 0; cg < NCG; cg++) S += psum[cg * 1024 + m] * expf(pmax[cg * 1024 + m] - M);
        local += M + logf(S) - tgt_logit[m];
    }
    __shared__ float red[256];
    red[tid] = local;
    __syncthreads();
    for (int s = 128; s > 0; s >>= 1) {
        if (tid < s) red[tid] += red[tid + s];
        __syncthreads();
    }
    if (tid == 0) out[0] = red[0] / (float)TDEC;
}

// ---------------------------------------------------------------------------
extern "C" void kernel_launch(void* const* d_in, const int* in_sizes, int n_in,
                              void* d_out, int out_size, void* d_ws, size_t ws_size,
                              hipStream_t stream)
{
    const int*   cw     = (const int*)  d_in[0];
    const int*   qw     = (const int*)  d_in[1];
    const float* emb_e  = (const float*)d_in[2];
    const float* emb_d  = (const float*)d_in[3];
    const float* Wih_e  = (const float*)d_in[4];
    const float* Whh_e  = (const float*)d_in[5];
    const float* bih_e  = (const float*)d_in[6];
    const float* bhh_e  = (const float*)d_in[7];
    const float* Wih_d  = (const float*)d_in[8];
    const float* Whh_d  = (const float*)d_in[9];
    const float* bih_d  = (const float*)d_in[10];
    const float* bhh_d  = (const float*)d_in[11];
    const float* Wg     = (const float*)d_in[12];
    const float* bg     = (const float*)d_in[13];

    // Workspace layout (floats); total ~59 MB
    float* ws      = (float*)d_ws;
    float* gx_enc  = ws;                                   // 8192*1536
    float* gx_dec  = gx_enc + (size_t)8192 * G3H;          // 1024*1536
    float* hbuf0   = gx_dec + (size_t)1024 * G3H;          // 32*512
    float* hbuf1   = hbuf0 + BB * HH;                      // 32*512
    float* h_all   = hbuf1 + BB * HH;                      // 1024*512
    float* pmax    = h_all + (size_t)1024 * HH;            // 49*1024
    float* psum    = pmax + NCG * 1024;                    // 49*1024
    float* tgt_l   = psum + NCG * 1024;                    // 1024

    // h0 = 0
    hipMemsetAsync(hbuf0, 0, BB * HH * sizeof(float), stream);

    // Phase 1: encoder gx (all timesteps in parallel)
    gx_kernel<<<dim3(512, 2), 256, 0, stream>>>(cw, emb_e, Wih_e, bih_e, gx_enc, 0);

    // Phase 2: encoder sequential scan (ping-pong h)
    for (int t = 0; t < TENC; t++) {
        const float* hin = (t & 1) ? hbuf1 : hbuf0;
        float*       hout = (t & 1) ? hbuf0 : hbuf1;
        gru_step_kernel<<<32, 256, 0, stream>>>(
            gx_enc + (size_t)t * BB * G3H, Whh_e, bhh_e, hin, hout);
    }
    // TENC even -> final h_enc lands in hbuf0

    // Phase 3: decoder gx (teacher forcing: inputs known ahead)
    gx_kernel<<<dim3(64, 2), 256, 0, stream>>>(qw, emb_d, Wih_d, bih_d, gx_dec, 1);

    // Phase 4: decoder scan, storing every h_t
    for (int t = 0; t < TDEC; t++) {
        const float* hin = (t == 0) ? hbuf0 : h_all + (size_t)(t - 1) * BB * HH;
        gru_step_kernel<<<32, 256, 0, stream>>>(
            gx_dec + (size_t)t * BB * G3H, Whh_d, bhh_d, hin, h_all + (size_t)t * BB * HH);
    }

    // Phase 5: batched logits + online logsumexp partials (one big GEMM)
    logits_kernel<<<dim3(64, NCG), 256, 0, stream>>>(h_all, Wg, bg, qw, pmax, psum, tgt_l);

    // Phase 6: combine partials -> scalar loss
    loss_kernel<<<1, 256, 0, stream>>>(pmax, psum, tgt_l, (float*)d_out);
}

// Round 2
// 4165.493 us; speedup vs baseline: 4.1054x; 4.1054x over previous
//
#include <hip/hip_runtime.h>
#include <math.h>

// Problem constants (from reference)
#define HH   512      // hidden
#define BB   32       // batch
#define TENC 256      // encoder steps
#define TDEC 32       // decoder steps
#define VV   50000    // vocab
#define SOSTOK 2
#define G3H  1536     // 3*H
#define NCG  49       // ceil(50000/1024) logits col-groups

__device__ __forceinline__ float sigmoidf_(float x) { return 1.0f / (1.0f + expf(-x)); }

// ---------------------------------------------------------------------------
// Transpose W [1536][512] -> WT [512][1536] (scalar, 32x32 LDS tiles).
// Makes gx GEMM weight loads j-contiguous (coalesced).
// grid = (512/32=16, 1536/32=48), block = 256.
// ---------------------------------------------------------------------------
__global__ __launch_bounds__(256) void transpose_w(
    const float* __restrict__ in, float* __restrict__ out)
{
    __shared__ float tile[32][33];
    const int kt = blockIdx.x * 32;   // over HH
    const int jt = blockIdx.y * 32;   // over G3H
    const int tx = threadIdx.x & 31, ty = threadIdx.x >> 5;  // 32 x 8
#pragma unroll
    for (int l = 0; l < 4; l++) {
        int j = jt + ty + l * 8;
        tile[ty + l * 8][tx] = in[(size_t)j * HH + kt + tx];
    }
    __syncthreads();
#pragma unroll
    for (int l = 0; l < 4; l++) {
        int k = kt + ty + l * 8;
        out[(size_t)k * G3H + jt + tx] = tile[tx][ty + l * 8];
    }
}

// ---------------------------------------------------------------------------
// Transpose Whh [1536][512] viewed as [1536][128] float4 -> WT4 [128][1536]
// float4. WT4[k4][j] = {Whh[j][4k4..4k4+3]}. Coalesced scan weight loads with
// 16B vectorization over k. grid = (128/16=8, 1536/16=96), block = 256.
// ---------------------------------------------------------------------------
__global__ __launch_bounds__(256) void transpose_w4(
    const float4* __restrict__ in, float4* __restrict__ out)
{
    __shared__ float4 tile[16][17];
    const int kt = blockIdx.x * 16;   // over 128
    const int jt = blockIdx.y * 16;   // over 1536
    const int tx = threadIdx.x & 15, ty = threadIdx.x >> 4;  // 16 x 16
    tile[ty][tx] = in[(size_t)(jt + ty) * 128 + kt + tx];
    __syncthreads();
    out[(size_t)(kt + ty) * G3H + jt + tx] = tile[tx][ty];
}

// ---------------------------------------------------------------------------
// gx kernel (TN, coalesced): out[m][j] = dot(A_row(m), WT[:,j]) + bias[j]
// WT is [512][1536] j-contiguous -> float4 weight loads are 1KB/wave-instr.
// A_row(m) = emb[idx(m)] (enc) or relu(emb[idx with SOS shift]) (dec).
// Block: 16 rows x 1024 cols. grid = (M/16, 2).
// ---------------------------------------------------------------------------
__global__ __launch_bounds__(256) void gxT_kernel(
    const int* __restrict__ idxs, const float* __restrict__ emb,
    const float* __restrict__ WT, const float* __restrict__ bias,
    float* __restrict__ out, int dec_mode)
{
    __shared__ __align__(16) float As[16][HH];
    const int tid = threadIdx.x;
    const int m0 = blockIdx.x * 16;

    for (int l = tid; l < 16 * HH; l += 256) {
        int r = l >> 9, k = l & (HH - 1);
        int m = m0 + r;
        int t = m >> 5, b = m & 31;
        int idx;
        if (dec_mode) idx = (t == 0) ? SOSTOK : idxs[b * TDEC + (t - 1)];
        else          idx = idxs[b * TENC + t];
        float v = emb[(size_t)idx * HH + k];
        if (dec_mode) v = fmaxf(v, 0.0f);
        As[r][k] = v;
    }
    __syncthreads();

    const int j0 = blockIdx.y * 1024 + tid * 4;
    if (j0 >= G3H) return;

    float acc[16][4];
#pragma unroll
    for (int r = 0; r < 16; r++)
#pragma unroll
        for (int jj = 0; jj < 4; jj++) acc[r][jj] = 0.0f;

    for (int kc = 0; kc < HH; kc += 4) {
        float4 w0 = *(const float4*)(WT + (size_t)(kc + 0) * G3H + j0);
        float4 w1 = *(const float4*)(WT + (size_t)(kc + 1) * G3H + j0);
        float4 w2 = *(const float4*)(WT + (size_t)(kc + 2) * G3H + j0);
        float4 w3 = *(const float4*)(WT + (size_t)(kc + 3) * G3H + j0);
#pragma unroll
        for (int r = 0; r < 16; r++) {
            float4 a = *(const float4*)(&As[r][kc]);
            acc[r][0] += a.x * w0.x + a.y * w1.x + a.z * w2.x + a.w * w3.x;
            acc[r][1] += a.x * w0.y + a.y * w1.y + a.z * w2.y + a.w * w3.y;
            acc[r][2] += a.x * w0.z + a.y * w1.z + a.z * w2.z + a.w * w3.z;
            acc[r][3] += a.x * w0.w + a.y * w1.w + a.z * w2.w + a.w * w3.w;
        }
    }

    float4 bv = *(const float4*)(bias + j0);
#pragma unroll
    for (int r = 0; r < 16; r++) {
        float4 o;
        o.x = acc[r][0] + bv.x;
        o.y = acc[r][1] + bv.y;
        o.z = acc[r][2] + bv.z;
        o.w = acc[r][3] + bv.w;
        *(float4*)(out + (size_t)(m0 + r) * G3H + j0) = o;
    }
}

// ---------------------------------------------------------------------------
// One GRU step, coalesced + k-split-4.
// grid = 256 blocks: bid = bq (b-quad, &7) | it<<3 (i-tile of 16).
// tid: wave = b within quad; lane = kq*16 + il (kq = k-quarter, il = i).
// Weights from WT4 [128][1536]f4: lanes read 4 x 256B segments per instr
// (same line count as fully coalesced). h quad staged in LDS (8KB).
// Partial dots reduced across kq with 2 shfl_xor. No LDS reduction.
// ---------------------------------------------------------------------------
__global__ __launch_bounds__(256) void gru_step3(
    const float4* __restrict__ WT4,   // [128][1536] float4
    const float* __restrict__ bhh,    // [3H]
    const float* __restrict__ gx_t,   // [B][3H] for this step (includes bih)
    const float* __restrict__ h_in,   // [B][H]
    float* __restrict__ h_out)        // [B][H]
{
    __shared__ float4 hs[512];        // 4 b's x 128 float4
    const int tid = threadIdx.x;
    const int bid = blockIdx.x;
    const int bq = bid & 7;           // b-quad
    const int it = bid >> 3;          // i-tile [0,32)
    const int bl = tid >> 6;          // wave index = b within quad
    const int lane = tid & 63;
    const int kq = lane >> 4;         // k-quarter [0,4)
    const int il = lane & 15;
    const int b = bq * 4 + bl;
    const int i = it * 16 + il;

    const float4* hin4 = (const float4*)h_in;
    hs[tid]       = hin4[bq * 512 + tid];
    hs[tid + 256] = hin4[bq * 512 + tid + 256];
    __syncthreads();

    const int k4base = kq * 32;
    const float4* hb = &hs[bl * 128 + k4base];
    const float4* wr = WT4 + (size_t)k4base * G3H + i;          // gate r
    const float4* wz = wr + HH;                                  // gate z
    const float4* wn = wr + 2 * HH;                              // gate n

    float ar = 0.f, az = 0.f, an = 0.f;
#pragma unroll 8
    for (int m = 0; m < 32; m++) {
        float4 h4 = hb[m];
        float4 w0 = wr[(size_t)m * G3H];
        float4 w1 = wz[(size_t)m * G3H];
        float4 w2 = wn[(size_t)m * G3H];
        ar += h4.x * w0.x + h4.y * w0.y + h4.z * w0.z + h4.w * w0.w;
        az += h4.x * w1.x + h4.y * w1.y + h4.z * w1.z + h4.w * w1.w;
        an += h4.x * w2.x + h4.y * w2.y + h4.z * w2.z + h4.w * w2.w;
    }

    // reduce across kq (lane bits 4,5)
    ar += __shfl_xor(ar, 16); az += __shfl_xor(az, 16); an += __shfl_xor(an, 16);
    ar += __shfl_xor(ar, 32); az += __shfl_xor(az, 32); an += __shfl_xor(an, 32);

    if (kq == 0) {
        float r = sigmoidf_(gx_t[b * G3H + i]            + ar + bhh[i]);
        float z = sigmoidf_(gx_t[b * G3H + HH + i]       + az + bhh[HH + i]);
        float n = tanhf    (gx_t[b * G3H + 2 * HH + i]   + r * (an + bhh[2 * HH + i]));
        float hp = h_in[b * HH + i];
        h_out[b * HH + i] = (1.0f - z) * n + z * hp;
    }
}

// ---------------------------------------------------------------------------
// Fused logits GEMM + per-row partial logsumexp + target-logit gather.
// (unchanged from round 1 — already coalesced, ~fp32 roofline)
// ---------------------------------------------------------------------------
__global__ __launch_bounds__(256) void logits_kernel(
    const float* __restrict__ Hall,   // [1024][512]
    const float* __restrict__ Wg,     // [512][50000]
    const float* __restrict__ bg,     // [50000]
    const int* __restrict__ qw,       // [32][32] targets
    float* __restrict__ pmax,         // [49][1024]
    float* __restrict__ psum,         // [49][1024]
    float* __restrict__ tgt_logit)    // [1024]
{
    __shared__ __align__(16) float As[16][HH];
    __shared__ float wred[16][4];
    const int tid = threadIdx.x;
    const int m0 = blockIdx.x * 16;
    const int lane = tid & 63, wid = tid >> 6;

    for (int l = tid; l < 16 * HH; l += 256) {
        int r = l >> 9, k = l & (HH - 1);
        As[r][k] = Hall[(size_t)(m0 + r) * HH + k];
    }
    __syncthreads();

    const int j0 = blockIdx.y * 1024 + tid * 4;
    const bool valid = (j0 < VV);

    float acc[16][4];
#pragma unroll
    for (int r = 0; r < 16; r++)
#pragma unroll
        for (int jj = 0; jj < 4; jj++) acc[r][jj] = 0.0f;

    if (valid) {
        for (int kc = 0; kc < HH; kc += 4) {
            float4 w0 = *(const float4*)(Wg + (size_t)(kc + 0) * VV + j0);
            float4 w1 = *(const float4*)(Wg + (size_t)(kc + 1) * VV + j0);
            float4 w2 = *(const float4*)(Wg + (size_t)(kc + 2) * VV + j0);
            float4 w3 = *(const float4*)(Wg + (size_t)(kc + 3) * VV + j0);
#pragma unroll
            for (int r = 0; r < 16; r++) {
                float4 a = *(const float4*)(&As[r][kc]);
                acc[r][0] += a.x * w0.x + a.y * w1.x + a.z * w2.x + a.w * w3.x;
                acc[r][1] += a.x * w0.y + a.y * w1.y + a.z * w2.y + a.w * w3.y;
                acc[r][2] += a.x * w0.z + a.y * w1.z + a.z * w2.z + a.w * w3.z;
                acc[r][3] += a.x * w0.w + a.y * w1.w + a.z * w2.w + a.w * w3.w;
            }
        }
        float4 bv = *(const float4*)(bg + j0);
#pragma unroll
        for (int r = 0; r < 16; r++) {
            acc[r][0] += bv.x; acc[r][1] += bv.y; acc[r][2] += bv.z; acc[r][3] += bv.w;
        }
#pragma unroll
        for (int r = 0; r < 16; r++) {
            int m = m0 + r, t = m >> 5, b = m & 31;
            int tj = qw[b * TDEC + t];
            if (tj >= j0 && tj < j0 + 4) tgt_logit[m] = acc[r][tj - j0];
        }
    }

    float rowmax[16];
#pragma unroll
    for (int r = 0; r < 16; r++) {
        float v = valid ? fmaxf(fmaxf(acc[r][0], acc[r][1]), fmaxf(acc[r][2], acc[r][3]))
                        : -INFINITY;
        for (int off = 32; off > 0; off >>= 1) v = fmaxf(v, __shfl_xor(v, off));
        if (lane == 0) wred[r][wid] = v;
    }
    __syncthreads();
#pragma unroll
    for (int r = 0; r < 16; r++)
        rowmax[r] = fmaxf(fmaxf(wred[r][0], wred[r][1]), fmaxf(wred[r][2], wred[r][3]));
    __syncthreads();

#pragma unroll
    for (int r = 0; r < 16; r++) {
        float s = 0.0f;
        if (valid) {
            s = expf(acc[r][0] - rowmax[r]) + expf(acc[r][1] - rowmax[r])
              + expf(acc[r][2] - rowmax[r]) + expf(acc[r][3] - rowmax[r]);
        }
        for (int off = 32; off > 0; off >>= 1) s += __shfl_xor(s, off);
        if (lane == 0) wred[r][wid] = s;
    }
    __syncthreads();

    if (tid < 16) {
        int r = tid;
        float S = wred[r][0] + wred[r][1] + wred[r][2] + wred[r][3];
        pmax[blockIdx.y * 1024 + m0 + r] = rowmax[r];
        psum[blockIdx.y * 1024 + m0 + r] = S;
    }
}

// ---------------------------------------------------------------------------
// Combine col-group partials -> per-row lse -> loss = sum(lse - tgt)/Tdec
// ---------------------------------------------------------------------------
__global__ __launch_bounds__(256) void loss_kernel(
    const float* __restrict__ pmax, const float* __restrict__ psum,
    const float* __restrict__ tgt_logit, float* __restrict__ out)
{
    const int tid = threadIdx.x;
    float local = 0.0f;
    for (int m = tid; m < 1024; m += 256) {
        float M = -INFINITY;
        for (int cg = 0; cg < NCG; cg++) M = fmaxf(M, pmax[cg * 1024 + m]);
        float S = 0.0f;
        for (int cg = 0; cg < NCG; cg++) S += psum[cg * 1024 + m] * expf(pmax[cg * 1024 + m] - M);
        local += M + logf(S) - tgt_logit[m];
    }
    __shared__ float red[256];
    red[tid] = local;
    __syncthreads();
    for (int s = 128; s > 0; s >>= 1) {
        if (tid < s) red[tid] += red[tid + s];
        __syncthreads();
    }
    if (tid == 0) out[0] = red[0] / (float)TDEC;
}

// ---------------------------------------------------------------------------
extern "C" void kernel_launch(void* const* d_in, const int* in_sizes, int n_in,
                              void* d_out, int out_size, void* d_ws, size_t ws_size,
                              hipStream_t stream)
{
    const int*   cw     = (const int*)  d_in[0];
    const int*   qw     = (const int*)  d_in[1];
    const float* emb_e  = (const float*)d_in[2];
    const float* emb_d  = (const float*)d_in[3];
    const float* Wih_e  = (const float*)d_in[4];
    const float* Whh_e  = (const float*)d_in[5];
    const float* bih_e  = (const float*)d_in[6];
    const float* bhh_e  = (const float*)d_in[7];
    const float* Wih_d  = (const float*)d_in[8];
    const float* Whh_d  = (const float*)d_in[9];
    const float* bih_d  = (const float*)d_in[10];
    const float* bhh_d  = (const float*)d_in[11];
    const float* Wg     = (const float*)d_in[12];
    const float* bg     = (const float*)d_in[13];

    // Workspace layout (floats); total ~72 MB
    float* ws      = (float*)d_ws;
    float* gx_enc  = ws;                                   // 8192*1536
    float* gx_dec  = gx_enc + (size_t)8192 * G3H;          // 1024*1536
    float* hbuf0   = gx_dec + (size_t)1024 * G3H;          // 32*512
    float* hbuf1   = hbuf0 + BB * HH;                      // 32*512
    float* h_all   = hbuf1 + BB * HH;                      // 1024*512
    float* pmax    = h_all + (size_t)1024 * HH;            // 49*1024
    float* psum    = pmax + NCG * 1024;                    // 49*1024
    float* tgt_l   = psum + NCG * 1024;                    // 1024
    float* WihT_e  = tgt_l + 1024;                         // 512*1536
    float* WihT_d  = WihT_e + (size_t)HH * G3H;            // 512*1536
    float* WhhT4_e = WihT_d + (size_t)HH * G3H;            // 512*1536 (as f4)
    float* WhhT4_d = WhhT4_e + (size_t)HH * G3H;           // 512*1536 (as f4)

    // h0 = 0
    hipMemsetAsync(hbuf0, 0, BB * HH * sizeof(float), stream);

    // Phase 0: weight transposes (coalesced layouts for gx and scan)
    transpose_w <<<dim3(16, 48), 256, 0, stream>>>(Wih_e, WihT_e);
    transpose_w <<<dim3(16, 48), 256, 0, stream>>>(Wih_d, WihT_d);
    transpose_w4<<<dim3(8, 96),  256, 0, stream>>>((const float4*)Whh_e, (float4*)WhhT4_e);
    transpose_w4<<<dim3(8, 96),  256, 0, stream>>>((const float4*)Whh_d, (float4*)WhhT4_d);

    // Phase 1: encoder gx (all timesteps in parallel)
    gxT_kernel<<<dim3(512, 2), 256, 0, stream>>>(cw, emb_e, WihT_e, bih_e, gx_enc, 0);

    // Phase 2: encoder sequential scan (ping-pong h)
    for (int t = 0; t < TENC; t++) {
        const float* hin = (t & 1) ? hbuf1 : hbuf0;
        float*       hout = (t & 1) ? hbuf0 : hbuf1;
        gru_step3<<<256, 256, 0, stream>>>(
            (const float4*)WhhT4_e, bhh_e, gx_enc + (size_t)t * BB * G3H, hin, hout);
    }
    // TENC even -> final h_enc lands in hbuf0

    // Phase 3: decoder gx (teacher forcing: inputs known ahead)
    gxT_kernel<<<dim3(64, 2), 256, 0, stream>>>(qw, emb_d, WihT_d, bih_d, gx_dec, 1);

    // Phase 4: decoder scan, storing every h_t
    for (int t = 0; t < TDEC; t++) {
        const float* hin = (t == 0) ? hbuf0 : h_all + (size_t)(t - 1) * BB * HH;
        gru_step3<<<256, 256, 0, stream>>>(
            (const float4*)WhhT4_d, bhh_d, gx_dec + (size_t)t * BB * G3H, hin,
            h_all + (size_t)t * BB * HH);
    }

    // Phase 5: batched logits + online logsumexp partials (one big GEMM)
    logits_kernel<<<dim3(64, NCG), 256, 0, stream>>>(h_all, Wg, bg, qw, pmax, psum, tgt_l);

    // Phase 6: combine partials -> scalar loss
    loss_kernel<<<1, 256, 0, stream>>>(pmax, psum, tgt_l, (float*)d_out);
}